// Round 6
// baseline (217.900 us; speedup 1.0000x reference)
//
#include <hip/hip_runtime.h>

// DCNv2 forward v5 — MFMA split-bf16 + counted-wait pipeline.
// K1 offconv_prep: zero(out) + offset-conv (16-way chan split) + dcn_w bf16 hi/lo prep
// K2 posprep: per-(tap,pos) pair-load meta (slot-permuted weights + row-base pair)
// K3 dcn_main: 1024 blocks, 64pos x 128o tile, 9 ksteps of 32k, 2-deep gather pipeline,
//              raw s_barrier + lgkmcnt(0) (no vmcnt drain), B direct-from-global,
//              atomicAdd epilogue into out.

#define CIN 128

typedef __attribute__((ext_vector_type(4))) float f32x4;
typedef __attribute__((ext_vector_type(8))) short bf16x8;

struct f2 { float x, y; };   // 4-byte-aligned float pair (pair-load)

__device__ __forceinline__ unsigned short f2bf(float f) {
    unsigned u = __float_as_uint(f);
    u += 0x7FFF + ((u >> 16) & 1);          // RNE
    return (unsigned short)(u >> 16);
}
__device__ __forceinline__ float bf2f(unsigned short h) {
    return __uint_as_float(((unsigned)h) << 16);
}

// ---------------- K1: zero-out + offset conv + weight prep ----------------
// blocks [0,1024): conv, 64 rowgroups x 16 cgroups(8ch); block 256 = 4 rows x 64 w
// blocks [1024,1600): wb prep  wb[S][o][k] (S = t*4 + c/32, k = c%32), hi/lo bf16
// blocks [1600,1664): zero d_out (for atomic epilogue)
__global__ __launch_bounds__(256) void offconv_prep(const float* __restrict__ x,
                                                    const float* __restrict__ ofw,
                                                    const float* __restrict__ dcn_w,
                                                    float* __restrict__ part,
                                                    unsigned short* __restrict__ wbh,
                                                    unsigned short* __restrict__ wbl,
                                                    float4* __restrict__ out4) {
    int bid = blockIdx.x;
    int tid = threadIdx.x;
    if (bid >= 1600) {
        int gid = (bid - 1600) * 256 + tid;          // < 16384
#pragma unroll
        for (int it = 0; it < 32; ++it)
            out4[it * 16384 + gid] = make_float4(0.f, 0.f, 0.f, 0.f);
        return;
    }
    if (bid >= 1024) {
        int i = (bid - 1024) * 256 + tid;            // < 147456
        int S = i >> 12, o = (i >> 5) & 127, k = i & 31;
        int c = ((S & 3) << 5) + k, t = S >> 2;
        float w = dcn_w[((o << 7) + c) * 9 + t];
        unsigned short h = f2bf(w);
        wbh[i] = h;
        wbl[i] = f2bf(w - bf2f(h));
        return;
    }
    int rg = bid >> 4, cg = bid & 15;
    int lr = tid >> 6, ow = tid & 63;
    int row = (rg << 2) + lr;                        // n*64 + oh
    int n = row >> 6, oh = row & 63;
    int c0 = cg << 3;

    float acc[27];
#pragma unroll
    for (int oc = 0; oc < 27; ++oc) acc[oc] = 0.f;

    const float* xb0 = x + ((n * CIN + c0) << 12) + (oh << 6) + ow;
#pragma unroll 1
    for (int cl = 0; cl < 8; ++cl) {
        const float* xb = xb0 + (cl << 12);
        float xv[9];
#pragma unroll
        for (int kh = 0; kh < 3; ++kh) {
            int ih = oh + kh - 1;
            bool okr = ((unsigned)ih < 64u);
#pragma unroll
            for (int kw = 0; kw < 3; ++kw) {
                int iw = ow + kw - 1;
                xv[kh * 3 + kw] = (okr && (unsigned)iw < 64u) ? xb[(kh - 1) * 64 + (kw - 1)] : 0.f;
            }
        }
        const float* wp = ofw + (c0 + cl) * 9;       // wave-uniform -> scalar loads
#pragma unroll
        for (int t = 0; t < 9; ++t) {
            float xvt = xv[t];
#pragma unroll
            for (int oc = 0; oc < 27; ++oc)
                acc[oc] = fmaf(xvt, wp[oc * 1152 + t], acc[oc]);
        }
    }
    int sp = (oh << 6) + ow;
#pragma unroll
    for (int oc = 0; oc < 27; ++oc)
        part[((((cg << 2) + n) * 27 + oc) << 12) + sp] = acc[oc];
}

// ---------------- K2: per-(tap,pos) meta, pair-load form ----------------
// wq = slot weights (s0r1, s1r1, s0r2, s1r2); ob = (R1*64+Cb) | (R2*64+Cb)<<16
__global__ __launch_bounds__(256) void posprep(const float* __restrict__ part,
                                               const float* __restrict__ ob,
                                               float4* __restrict__ wq_t,
                                               unsigned* __restrict__ ob_t) {
    int gid = blockIdx.x * 256 + threadIdx.x;        // < 147456
    int k = gid >> 14, pos = gid & 16383;
    int n = pos >> 12, sp = pos & 4095;
    int oh = sp >> 6, ow = sp & 63;

    float oy = ob[2 * k], ox = ob[2 * k + 1], os = ob[18 + k];
#pragma unroll
    for (int cg = 0; cg < 16; ++cg) {
        const float* pb = part + ((((cg << 2) + n) * 27) << 12) + sp;
        oy += pb[(2 * k) << 12];
        ox += pb[(2 * k + 1) << 12];
        os += pb[(18 + k) << 12];
    }
    float m = 1.f / (1.f + expf(-os));
    float py = fminf(fmaxf((float)(oh + k / 3) + oy, 0.f), 65.f);
    float px = fminf(fmaxf((float)(ow + k % 3) + ox, 0.f), 65.f);
    float y1f = floorf(py), x1f = floorf(px);
    float lh = py - y1f, lw = px - x1f;
    float hh = 1.f - lh, hw = 1.f - lw;
    int y1 = (int)y1f, x1 = (int)x1f;
    int r1 = y1 - 1, r2 = y1, c1 = x1 - 1, c2 = x1;  // padded -> real coords; c2 = c1+1
    bool vr1 = (unsigned)r1 < 64u, vr2 = (unsigned)r2 < 64u;
    bool vc1 = (unsigned)c1 < 64u, vc2 = (unsigned)c2 < 64u;
    float w1 = (vr1 && vc1) ? hh * hw * m : 0.f;
    float w2 = (vr1 && vc2) ? hh * lw * m : 0.f;
    float w3 = (vr2 && vc1) ? lh * hw * m : 0.f;
    float w4 = (vr2 && vc2) ? lh * lw * m : 0.f;
    int Cb = min(max(c1, 0), 62);
    bool a0 = (c1 == Cb);                            // corner1 in slot0 (normal case)
    float s0r1 = a0 ? w1 : ((c2 == Cb) ? w2 : 0.f);
    float s1r1 = a0 ? w2 : ((c1 == Cb + 1) ? w1 : 0.f);
    float s0r2 = a0 ? w3 : ((c2 == Cb) ? w4 : 0.f);
    float s1r2 = a0 ? w4 : ((c1 == Cb + 1) ? w3 : 0.f);
    int R1 = min(max(r1, 0), 63), R2 = min(max(r2, 0), 63);
    unsigned o1 = (unsigned)(R1 * 64 + Cb), o2 = (unsigned)(R2 * 64 + Cb);
    wq_t[(k << 14) + pos] = make_float4(s0r1, s1r1, s0r2, s1r2);
    ob_t[(k << 14) + pos] = o1 | (o2 << 16);
}

// ---------------- K3: MFMA gather-GEMM, counted-wait pipeline ----------------
// grid 1024 = 256 pos-tiles(64) x 4 kq; block 256 = 4 waves; wave = 32 pos x 64 o.
// 9 ksteps of 32k; gathers 2-deep in registers; B direct from global (1-step ahead);
// LDS = A hi/lo dbuf 16KB, XOR unit-swizzle; raw s_barrier (no vmcnt drain).
__global__ __launch_bounds__(256, 2) void dcn_main(const float* __restrict__ x,
                                                   const float4* __restrict__ wq_t,
                                                   const unsigned* __restrict__ ob_t,
                                                   const unsigned short* __restrict__ wbh,
                                                   const unsigned short* __restrict__ wbl,
                                                   float* __restrict__ out) {
    __shared__ short Ah[2][2048];                    // [buf][64 pos][32 k], 16B-unit swizzled
    __shared__ short Al[2][2048];

    int b0 = blockIdx.x;
    int bid = ((b0 & 7) << 7) | (b0 >> 3);           // XCD swizzle (1024 = 8*128)
    int tile = bid >> 2, q = bid & 3;
    int p0 = tile << 6;
    int tid = threadIdx.x;
    int lane = tid & 63, wave = tid >> 6;
    int ph = wave >> 1, ohf = wave & 1;              // pos-half(32), o-half(64)
    int fr = lane & 15, fg = lane >> 4;
    int gp = tid & 63, gc = tid >> 6;                // gather: pos, 8-ch group (gc==wave)
    int pos = p0 + gp;
    int n = pos >> 12;                               // block-uniform (64 | 4096)
    const float* xn = x + ((long)n << 19);
    int S0 = q * 9;
    int hwbase = p0 & 4095;

    f32x4 acc[2][4];
#pragma unroll
    for (int i = 0; i < 2; ++i)
#pragma unroll
        for (int j = 0; j < 4; ++j) acc[i][j] = (f32x4)0.f;

    f2 g1[2][8], g2[2][8];
    float4 wv[2];
    bf16x8 bh[4], bl[4];

#define GATHER(P, S_) do {                                                          \
    int t_ = (S_) >> 2;                                                             \
    wv[P] = wq_t[(t_ << 14) + pos];                                                 \
    unsigned obp_ = ob_t[(t_ << 14) + pos];                                         \
    int o1_ = (int)(obp_ & 0xffffu), o2_ = (int)(obp_ >> 16);                       \
    const float* xb_ = xn + ((long)((((S_) & 3) << 5) + (gc << 3)) << 12);          \
    _Pragma("unroll")                                                               \
    for (int e_ = 0; e_ < 8; ++e_) {                                                \
        const float* xc_ = xb_ + (e_ << 12);                                        \
        g1[P][e_] = *(const f2*)(xc_ + o1_);                                        \
        g2[P][e_] = *(const f2*)(xc_ + o2_);                                        \
    }                                                                               \
} while (0)

#define PACK(P, BUF) do {                                                           \
    bf16x8 vh_, vl_;                                                                \
    _Pragma("unroll")                                                               \
    for (int e_ = 0; e_ < 8; ++e_) {                                                \
        float v_ = wv[P].x * g1[P][e_].x + wv[P].y * g1[P][e_].y                    \
                 + wv[P].z * g2[P][e_].x + wv[P].w * g2[P][e_].y;                   \
        unsigned short h_ = f2bf(v_);                                               \
        vh_[e_] = (short)h_;                                                        \
        vl_[e_] = (short)f2bf(v_ - bf2f(h_));                                       \
    }                                                                               \
    int u_ = (gc ^ (gp & 3) ^ ((gp >> 2) & 3) ^ ((gp >> 4) & 3)) & 3;               \
    *(bf16x8*)&Ah[BUF][(gp << 5) + (u_ << 3)] = vh_;                                \
    *(bf16x8*)&Al[BUF][(gp << 5) + (u_ << 3)] = vl_;                                \
} while (0)

#define LOADB(S_) do {                                                              \
    _Pragma("unroll")                                                               \
    for (int j_ = 0; j_ < 4; ++j_) {                                                \
        int ob_ = (ohf << 6) + (j_ << 4) + fr;                                      \
        long a_ = ((long)(S_) << 12) + (ob_ << 5) + (fg << 3);                      \
        bh[j_] = *(const bf16x8*)(wbh + a_);                                        \
        bl[j_] = *(const bf16x8*)(wbl + a_);                                        \
    }                                                                               \
} while (0)

#define STEP(BUF) do {                                                              \
    bf16x8 ah_[2], al_[2];                                                          \
    _Pragma("unroll")                                                               \
    for (int i_ = 0; i_ < 2; ++i_) {                                                \
        int pl_ = (ph << 5) + (i_ << 4) + fr;                                       \
        int u_ = (fg ^ (pl_ & 3) ^ ((pl_ >> 2) & 3) ^ ((pl_ >> 4) & 3)) & 3;        \
        ah_[i_] = *(const bf16x8*)&Ah[BUF][(pl_ << 5) + (u_ << 3)];                 \
        al_[i_] = *(const bf16x8*)&Al[BUF][(pl_ << 5) + (u_ << 3)];                 \
    }                                                                               \
    __builtin_amdgcn_s_setprio(1);                                                  \
    _Pragma("unroll")                                                               \
    for (int j_ = 0; j_ < 4; ++j_) {                                                \
        _Pragma("unroll")                                                           \
        for (int i_ = 0; i_ < 2; ++i_) {                                            \
            acc[i_][j_] = __builtin_amdgcn_mfma_f32_16x16x32_bf16(ah_[i_], bh[j_], acc[i_][j_], 0, 0, 0); \
            acc[i_][j_] = __builtin_amdgcn_mfma_f32_16x16x32_bf16(al_[i_], bh[j_], acc[i_][j_], 0, 0, 0); \
            acc[i_][j_] = __builtin_amdgcn_mfma_f32_16x16x32_bf16(ah_[i_], bl[j_], acc[i_][j_], 0, 0, 0); \
        }                                                                           \
    }                                                                               \
    __builtin_amdgcn_s_setprio(0);                                                  \
} while (0)

// raw barrier: LDS-visibility wait only — NO vmcnt drain (prefetches stay in flight)
#define BAR() do {                                                                  \
    asm volatile("s_waitcnt lgkmcnt(0)" ::: "memory");                              \
    __builtin_amdgcn_sched_barrier(0);                                              \
    __builtin_amdgcn_s_barrier();                                                   \
    __builtin_amdgcn_sched_barrier(0);                                              \
} while (0)

    // prologue: 2-deep gather, 1-deep B, pack step0
    GATHER(0, S0);
    GATHER(1, S0 + 1);
    LOADB(S0);
    PACK(0, 0);
    BAR();

#pragma unroll
    for (int s = 0; s < 9; ++s) {
        if (s + 2 <= 8) GATHER(s & 1, S0 + s + 2);   // refill the set packed last step
        STEP(s & 1);                                 // consumes bh/bl = B(s)
        if (s < 8) {
            LOADB(S0 + s + 1);                       // B one step ahead
            PACK((s + 1) & 1, (s + 1) & 1);          // gathers issued 2 steps ago
            BAR();
        }
    }

    // epilogue: atomic accumulate into out[n][o][hw] (zeroed by K1)
    float* on_ = out + (((long)n) << 19);
#pragma unroll
    for (int i = 0; i < 2; ++i) {
#pragma unroll
        for (int j = 0; j < 4; ++j) {
            int o = (ohf << 6) + (j << 4) + fr;
            int hw0 = hwbase + (ph << 5) + (i << 4) + (fg << 2);
            float* dst = on_ + (((long)o) << 12) + hw0;
            atomicAdd(dst + 0, acc[i][j][0]);
            atomicAdd(dst + 1, acc[i][j][1]);
            atomicAdd(dst + 2, acc[i][j][2]);
            atomicAdd(dst + 3, acc[i][j][3]);
        }
    }
#undef GATHER
#undef PACK
#undef LOADB
#undef STEP
#undef BAR
}

extern "C" void kernel_launch(void* const* d_in, const int* in_sizes, int n_in,
                              void* d_out, int out_size, void* d_ws, size_t ws_size,
                              hipStream_t stream) {
    const float* x     = (const float*)d_in[0];      // [4,128,64,64]
    const float* ofw   = (const float*)d_in[1];      // [27,128,3,3]
    const float* ob    = (const float*)d_in[2];      // [27]
    const float* dcn_w = (const float*)d_in[3];      // [128,128,3,3]
    float* out = (float*)d_out;                      // [4,128,64,64]

    char* ws = (char*)d_ws;
    float*          part = (float*)ws;                        // 28,311,552 B
    float4*         wq_t = (float4*)(ws + 28311552);          //  2,359,296 B
    unsigned*       ob_t = (unsigned*)(ws + 30670848);        //    589,824 B
    unsigned short* wbh  = (unsigned short*)(ws + 31260672);  //    294,912 B
    unsigned short* wbl  = (unsigned short*)(ws + 31555584);  //    294,912 B
    // total 31,850,496 B (< 44.7 MB proven budget)

    offconv_prep<<<dim3(1664), dim3(256), 0, stream>>>(x, ofw, dcn_w, part, wbh, wbl, (float4*)out);
    posprep<<<dim3(576), dim3(256), 0, stream>>>(part, ob, wq_t, ob_t);
    dcn_main<<<dim3(1024), dim3(256), 0, stream>>>(x, wq_t, ob_t, wbh, wbl, out);
}

// Round 8
// 212.017 us; speedup vs baseline: 1.0277x; 1.0277x over previous
//
#include <hip/hip_runtime.h>

// DCNv2 forward v6 — v5 pipeline with pout/combine epilogue (atomics reverted).
// (Resubmit: R7 bench was an acquisition timeout; source unchanged from R7 submission.)
// K1 offconv_prep: offset-conv (8-way chan split) + dcn_w bf16 hi/lo prep
// K2 posprep: per-(tap,pos) pair-load meta (slot-permuted weights + row-base pair)
// K3 dcn_main: 1024 blocks = 256 pos-tiles(64) x 4 kq, raw barriers (no vmcnt drain),
//              2-deep register gather pipeline, B direct-from-global, pout f4 stores.
// K4 combine: sum 4 K-partials, fully coalesced.

#define CIN 128

typedef __attribute__((ext_vector_type(4))) float f32x4;
typedef __attribute__((ext_vector_type(8))) short bf16x8;

struct f2 { float x, y; };   // 4-byte-aligned float pair (pair-load)

__device__ __forceinline__ unsigned short f2bf(float f) {
    unsigned u = __float_as_uint(f);
    u += 0x7FFF + ((u >> 16) & 1);          // RNE
    return (unsigned short)(u >> 16);
}
__device__ __forceinline__ float bf2f(unsigned short h) {
    return __uint_as_float(((unsigned)h) << 16);
}

// ---------------- K1: offset conv + weight prep ----------------
// blocks [0,512): conv, 64 rowgroups x 8 cgroups(16ch); block 256 = 4 rows x 64 w
// blocks [512,1088): wb prep  wb[S][o][k] (S = t*4 + c/32, k = c%32), hi/lo bf16
__global__ __launch_bounds__(256) void offconv_prep(const float* __restrict__ x,
                                                    const float* __restrict__ ofw,
                                                    const float* __restrict__ dcn_w,
                                                    float* __restrict__ part,
                                                    unsigned short* __restrict__ wbh,
                                                    unsigned short* __restrict__ wbl) {
    int bid = blockIdx.x;
    int tid = threadIdx.x;
    if (bid >= 512) {
        int i = (bid - 512) * 256 + tid;             // < 147456
        int S = i >> 12, o = (i >> 5) & 127, k = i & 31;
        int c = ((S & 3) << 5) + k, t = S >> 2;
        float w = dcn_w[((o << 7) + c) * 9 + t];
        unsigned short h = f2bf(w);
        wbh[i] = h;
        wbl[i] = f2bf(w - bf2f(h));
        return;
    }
    int rg = bid >> 3, cg = bid & 7;
    int lr = tid >> 6, ow = tid & 63;
    int row = (rg << 2) + lr;                        // n*64 + oh
    int n = row >> 6, oh = row & 63;
    int c0 = cg << 4;

    float acc[27];
#pragma unroll
    for (int oc = 0; oc < 27; ++oc) acc[oc] = 0.f;

    const float* xb0 = x + ((n * CIN + c0) << 12) + (oh << 6) + ow;
#pragma unroll 1
    for (int cl = 0; cl < 16; ++cl) {
        const float* xb = xb0 + (cl << 12);
        float xv[9];
#pragma unroll
        for (int kh = 0; kh < 3; ++kh) {
            int ih = oh + kh - 1;
            bool okr = ((unsigned)ih < 64u);
#pragma unroll
            for (int kw = 0; kw < 3; ++kw) {
                int iw = ow + kw - 1;
                xv[kh * 3 + kw] = (okr && (unsigned)iw < 64u) ? xb[(kh - 1) * 64 + (kw - 1)] : 0.f;
            }
        }
        const float* wp = ofw + (c0 + cl) * 9;       // wave-uniform -> scalar loads
#pragma unroll
        for (int t = 0; t < 9; ++t) {
            float xvt = xv[t];
#pragma unroll
            for (int oc = 0; oc < 27; ++oc)
                acc[oc] = fmaf(xvt, wp[oc * 1152 + t], acc[oc]);
        }
    }
    int sp = (oh << 6) + ow;
#pragma unroll
    for (int oc = 0; oc < 27; ++oc)
        part[((((cg << 2) + n) * 27 + oc) << 12) + sp] = acc[oc];
}

// ---------------- K2: per-(tap,pos) meta, pair-load form ----------------
// wq = slot weights (s0r1, s1r1, s0r2, s1r2); ob = (R1*64+Cb) | (R2*64+Cb)<<16
__global__ __launch_bounds__(256) void posprep(const float* __restrict__ part,
                                               const float* __restrict__ ob,
                                               float4* __restrict__ wq_t,
                                               unsigned* __restrict__ ob_t) {
    int gid = blockIdx.x * 256 + threadIdx.x;        // < 147456
    int k = gid >> 14, pos = gid & 16383;
    int n = pos >> 12, sp = pos & 4095;
    int oh = sp >> 6, ow = sp & 63;

    float oy = ob[2 * k], ox = ob[2 * k + 1], os = ob[18 + k];
#pragma unroll
    for (int cg = 0; cg < 8; ++cg) {
        const float* pb = part + ((((cg << 2) + n) * 27) << 12) + sp;
        oy += pb[(2 * k) << 12];
        ox += pb[(2 * k + 1) << 12];
        os += pb[(18 + k) << 12];
    }
    float m = 1.f / (1.f + expf(-os));
    float py = fminf(fmaxf((float)(oh + k / 3) + oy, 0.f), 65.f);
    float px = fminf(fmaxf((float)(ow + k % 3) + ox, 0.f), 65.f);
    float y1f = floorf(py), x1f = floorf(px);
    float lh = py - y1f, lw = px - x1f;
    float hh = 1.f - lh, hw = 1.f - lw;
    int y1 = (int)y1f, x1 = (int)x1f;
    int r1 = y1 - 1, r2 = y1, c1 = x1 - 1, c2 = x1;  // padded -> real coords; c2 = c1+1
    bool vr1 = (unsigned)r1 < 64u, vr2 = (unsigned)r2 < 64u;
    bool vc1 = (unsigned)c1 < 64u, vc2 = (unsigned)c2 < 64u;
    float w1 = (vr1 && vc1) ? hh * hw * m : 0.f;
    float w2 = (vr1 && vc2) ? hh * lw * m : 0.f;
    float w3 = (vr2 && vc1) ? lh * hw * m : 0.f;
    float w4 = (vr2 && vc2) ? lh * lw * m : 0.f;
    int Cb = min(max(c1, 0), 62);
    bool a0 = (c1 == Cb);                            // corner1 in slot0 (normal case)
    float s0r1 = a0 ? w1 : ((c2 == Cb) ? w2 : 0.f);
    float s1r1 = a0 ? w2 : ((c1 == Cb + 1) ? w1 : 0.f);
    float s0r2 = a0 ? w3 : ((c2 == Cb) ? w4 : 0.f);
    float s1r2 = a0 ? w4 : ((c1 == Cb + 1) ? w3 : 0.f);
    int R1 = min(max(r1, 0), 63), R2 = min(max(r2, 0), 63);
    unsigned o1 = (unsigned)(R1 * 64 + Cb), o2 = (unsigned)(R2 * 64 + Cb);
    wq_t[(k << 14) + pos] = make_float4(s0r1, s1r1, s0r2, s1r2);
    ob_t[(k << 14) + pos] = o1 | (o2 << 16);
}

// ---------------- K3: MFMA gather-GEMM, counted-wait pipeline ----------------
// grid 1024 = 256 pos-tiles(64) x 4 kq; block 256 = 4 waves; wave = 32 pos x 64 o.
// 9 ksteps of 32k; gathers 2-deep in registers; B direct from global (1-step ahead);
// LDS = A hi/lo dbuf 16KB, XOR unit-swizzle; raw s_barrier (no vmcnt drain).
__global__ __launch_bounds__(256, 4) void dcn_main(const float* __restrict__ x,
                                                   const float4* __restrict__ wq_t,
                                                   const unsigned* __restrict__ ob_t,
                                                   const unsigned short* __restrict__ wbh,
                                                   const unsigned short* __restrict__ wbl,
                                                   float* __restrict__ pout) {
    __shared__ short Ah[2][2048];                    // [buf][64 pos][32 k], 16B-unit swizzled
    __shared__ short Al[2][2048];

    int b0 = blockIdx.x;
    int bid = ((b0 & 7) << 7) | (b0 >> 3);           // XCD swizzle (1024 = 8*128)
    int tile = bid >> 2, q = bid & 3;
    int p0 = tile << 6;
    int tid = threadIdx.x;
    int lane = tid & 63, wave = tid >> 6;
    int ph = wave >> 1, ohf = wave & 1;              // pos-half(32), o-half(64)
    int fr = lane & 15, fg = lane >> 4;
    int gp = tid & 63, gc = tid >> 6;                // gather: pos, 8-ch group (gc==wave)
    int pos = p0 + gp;
    int n = pos >> 12;                               // block-uniform (64 | 4096)
    const float* xn = x + ((long)n << 19);
    int S0 = q * 9;

    f32x4 acc[2][4];
#pragma unroll
    for (int i = 0; i < 2; ++i)
#pragma unroll
        for (int j = 0; j < 4; ++j) acc[i][j] = (f32x4)0.f;

    f2 g1[2][8], g2[2][8];
    float4 wv[2];
    bf16x8 bh[4], bl[4];

#define GATHER(P, S_) do {                                                          \
    int t_ = (S_) >> 2;                                                             \
    wv[P] = wq_t[(t_ << 14) + pos];                                                 \
    unsigned obp_ = ob_t[(t_ << 14) + pos];                                         \
    int o1_ = (int)(obp_ & 0xffffu), o2_ = (int)(obp_ >> 16);                       \
    const float* xb_ = xn + ((long)((((S_) & 3) << 5) + (gc << 3)) << 12);          \
    _Pragma("unroll")                                                               \
    for (int e_ = 0; e_ < 8; ++e_) {                                                \
        const float* xc_ = xb_ + (e_ << 12);                                        \
        g1[P][e_] = *(const f2*)(xc_ + o1_);                                        \
        g2[P][e_] = *(const f2*)(xc_ + o2_);                                        \
    }                                                                               \
} while (0)

#define PACK(P, BUF) do {                                                           \
    bf16x8 vh_, vl_;                                                                \
    _Pragma("unroll")                                                               \
    for (int e_ = 0; e_ < 8; ++e_) {                                                \
        float v_ = wv[P].x * g1[P][e_].x + wv[P].y * g1[P][e_].y                    \
                 + wv[P].z * g2[P][e_].x + wv[P].w * g2[P][e_].y;                   \
        unsigned short h_ = f2bf(v_);                                               \
        vh_[e_] = (short)h_;                                                        \
        vl_[e_] = (short)f2bf(v_ - bf2f(h_));                                       \
    }                                                                               \
    int u_ = (gc ^ (gp & 3) ^ ((gp >> 2) & 3) ^ ((gp >> 4) & 3)) & 3;               \
    *(bf16x8*)&Ah[BUF][(gp << 5) + (u_ << 3)] = vh_;                                \
    *(bf16x8*)&Al[BUF][(gp << 5) + (u_ << 3)] = vl_;                                \
} while (0)

#define LOADB(S_) do {                                                              \
    _Pragma("unroll")                                                               \
    for (int j_ = 0; j_ < 4; ++j_) {                                                \
        int ob_ = (ohf << 6) + (j_ << 4) + fr;                                      \
        long a_ = ((long)(S_) << 12) + (ob_ << 5) + (fg << 3);                      \
        bh[j_] = *(const bf16x8*)(wbh + a_);                                        \
        bl[j_] = *(const bf16x8*)(wbl + a_);                                        \
    }                                                                               \
} while (0)

#define STEP(BUF) do {                                                              \
    bf16x8 ah_[2], al_[2];                                                          \
    _Pragma("unroll")                                                               \
    for (int i_ = 0; i_ < 2; ++i_) {                                                \
        int pl_ = (ph << 5) + (i_ << 4) + fr;                                       \
        int u_ = (fg ^ (pl_ & 3) ^ ((pl_ >> 2) & 3) ^ ((pl_ >> 4) & 3)) & 3;        \
        ah_[i_] = *(const bf16x8*)&Ah[BUF][(pl_ << 5) + (u_ << 3)];                 \
        al_[i_] = *(const bf16x8*)&Al[BUF][(pl_ << 5) + (u_ << 3)];                 \
    }                                                                               \
    __builtin_amdgcn_s_setprio(1);                                                  \
    _Pragma("unroll")                                                               \
    for (int j_ = 0; j_ < 4; ++j_) {                                                \
        _Pragma("unroll")                                                           \
        for (int i_ = 0; i_ < 2; ++i_) {                                            \
            acc[i_][j_] = __builtin_amdgcn_mfma_f32_16x16x32_bf16(ah_[i_], bh[j_], acc[i_][j_], 0, 0, 0); \
            acc[i_][j_] = __builtin_amdgcn_mfma_f32_16x16x32_bf16(al_[i_], bh[j_], acc[i_][j_], 0, 0, 0); \
            acc[i_][j_] = __builtin_amdgcn_mfma_f32_16x16x32_bf16(ah_[i_], bl[j_], acc[i_][j_], 0, 0, 0); \
        }                                                                           \
    }                                                                               \
    __builtin_amdgcn_s_setprio(0);                                                  \
} while (0)

// raw barrier: LDS-visibility wait only — NO vmcnt drain (prefetches stay in flight)
#define BAR() do {                                                                  \
    asm volatile("s_waitcnt lgkmcnt(0)" ::: "memory");                              \
    __builtin_amdgcn_sched_barrier(0);                                              \
    __builtin_amdgcn_s_barrier();                                                   \
    __builtin_amdgcn_sched_barrier(0);                                              \
} while (0)

    // prologue: 2-deep gather, 1-deep B, pack step0
    GATHER(0, S0);
    GATHER(1, S0 + 1);
    LOADB(S0);
    PACK(0, 0);
    BAR();

#pragma unroll
    for (int s = 0; s < 9; ++s) {
        if (s + 2 <= 8) GATHER(s & 1, S0 + s + 2);   // refill the set packed last step
        STEP(s & 1);                                 // consumes bh/bl = B(s)
        if (s < 8) {
            LOADB(S0 + s + 1);                       // B one step ahead
            PACK((s + 1) & 1, (s + 1) & 1);          // gathers issued 2 steps ago
            BAR();
        }
    }

    // epilogue: pout[q][o][pos] (o-major) — each lane stores contiguous float4
    float* op = pout + ((long)q << 21);
#pragma unroll
    for (int i = 0; i < 2; ++i) {
        int pp = p0 + (ph << 5) + (i << 4) + (fg << 2);
#pragma unroll
        for (int j = 0; j < 4; ++j) {
            int o = (ohf << 6) + (j << 4) + fr;
            float4 st = make_float4(acc[i][j][0], acc[i][j][1], acc[i][j][2], acc[i][j][3]);
            *(float4*)(op + ((long)o << 14) + pp) = st;
        }
    }
#undef GATHER
#undef PACK
#undef LOADB
#undef STEP
#undef BAR
}

// ---------------- K4: sum 4 K-partials, fully coalesced ----------------
// pout[q][o][pos], pos = n*4096+hw ; out[n][o][hw]. grid 2048 x 256 over float4s.
__global__ __launch_bounds__(256) void combine(const float4* __restrict__ pout4,
                                               float4* __restrict__ out4) {
    int i = blockIdx.x * 256 + threadIdx.x;          // < 524288
    int o = i >> 12, rem = i & 4095;
    int n = rem >> 10, hw4 = rem & 1023;
    float4 a = pout4[i];
    float4 b = pout4[i + (1 << 19)];
    float4 c = pout4[i + (2 << 19)];
    float4 d = pout4[i + (3 << 19)];
    float4 r = make_float4(a.x + b.x + c.x + d.x, a.y + b.y + c.y + d.y,
                           a.z + b.z + c.z + d.z, a.w + b.w + c.w + d.w);
    out4[(n << 17) + (o << 10) + hw4] = r;
}

extern "C" void kernel_launch(void* const* d_in, const int* in_sizes, int n_in,
                              void* d_out, int out_size, void* d_ws, size_t ws_size,
                              hipStream_t stream) {
    const float* x     = (const float*)d_in[0];      // [4,128,64,64]
    const float* ofw   = (const float*)d_in[1];      // [27,128,3,3]
    const float* ob    = (const float*)d_in[2];      // [27]
    const float* dcn_w = (const float*)d_in[3];      // [128,128,3,3]
    float* out = (float*)d_out;                      // [4,128,64,64]

    char* ws = (char*)d_ws;
    // pout (K3/K4) overlaps part (K1/K2) — disjoint lifetimes
    float*          pout = (float*)ws;                        // 33,554,432 B
    float*          part = (float*)ws;                        // 14,155,776 B (overlap)
    float4*         wq_t = (float4*)(ws + 33554432);          //  2,359,296 B
    unsigned*       ob_t = (unsigned*)(ws + 35913728);        //    589,824 B
    unsigned short* wbh  = (unsigned short*)(ws + 36503552);  //    294,912 B
    unsigned short* wbl  = (unsigned short*)(ws + 36798464);  //    294,912 B
    // total 37,093,376 B (< 44.7 MB proven budget)

    offconv_prep<<<dim3(1088), dim3(256), 0, stream>>>(x, ofw, dcn_w, part, wbh, wbl);
    posprep<<<dim3(576), dim3(256), 0, stream>>>(part, ob, wq_t, ob_t);
    dcn_main<<<dim3(1024), dim3(256), 0, stream>>>(x, wq_t, ob_t, wbh, wbl, pout);
    combine<<<dim3(2048), dim3(256), 0, stream>>>((const float4*)pout, (float4*)out);
}

// Round 9
// 166.282 us; speedup vs baseline: 1.3104x; 1.2750x over previous
//
#include <hip/hip_runtime.h>

// DCNv2 forward v7 — v6 with the spill fixed: __launch_bounds__(256,2) on dcn_main.
// (R8 post-mortem: (256,4) capped VGPR at 128 -> ~300MB/dispatch scratch spill traffic.)
// K1 offconv_prep: offset-conv (8-way chan split) + dcn_w bf16 hi/lo prep
// K2 posprep: per-(tap,pos) pair-load meta (slot-permuted weights + row-base pair)
// K3 dcn_main: 1024 blocks = 256 pos-tiles(64) x 4 kq, raw barriers (no vmcnt drain),
//              2-deep register gather pipeline, B direct-from-global, pout f4 stores.
// K4 combine: sum 4 K-partials, fully coalesced.

#define CIN 128

typedef __attribute__((ext_vector_type(4))) float f32x4;
typedef __attribute__((ext_vector_type(8))) short bf16x8;

struct f2 { float x, y; };   // 4-byte-aligned float pair (pair-load)

__device__ __forceinline__ unsigned short f2bf(float f) {
    unsigned u = __float_as_uint(f);
    u += 0x7FFF + ((u >> 16) & 1);          // RNE
    return (unsigned short)(u >> 16);
}
__device__ __forceinline__ float bf2f(unsigned short h) {
    return __uint_as_float(((unsigned)h) << 16);
}

// ---------------- K1: offset conv + weight prep ----------------
// blocks [0,512): conv, 64 rowgroups x 8 cgroups(16ch); block 256 = 4 rows x 64 w
// blocks [512,1088): wb prep  wb[S][o][k] (S = t*4 + c/32, k = c%32), hi/lo bf16
__global__ __launch_bounds__(256) void offconv_prep(const float* __restrict__ x,
                                                    const float* __restrict__ ofw,
                                                    const float* __restrict__ dcn_w,
                                                    float* __restrict__ part,
                                                    unsigned short* __restrict__ wbh,
                                                    unsigned short* __restrict__ wbl) {
    int bid = blockIdx.x;
    int tid = threadIdx.x;
    if (bid >= 512) {
        int i = (bid - 512) * 256 + tid;             // < 147456
        int S = i >> 12, o = (i >> 5) & 127, k = i & 31;
        int c = ((S & 3) << 5) + k, t = S >> 2;
        float w = dcn_w[((o << 7) + c) * 9 + t];
        unsigned short h = f2bf(w);
        wbh[i] = h;
        wbl[i] = f2bf(w - bf2f(h));
        return;
    }
    int rg = bid >> 3, cg = bid & 7;
    int lr = tid >> 6, ow = tid & 63;
    int row = (rg << 2) + lr;                        // n*64 + oh
    int n = row >> 6, oh = row & 63;
    int c0 = cg << 4;

    float acc[27];
#pragma unroll
    for (int oc = 0; oc < 27; ++oc) acc[oc] = 0.f;

    const float* xb0 = x + ((n * CIN + c0) << 12) + (oh << 6) + ow;
#pragma unroll 1
    for (int cl = 0; cl < 16; ++cl) {
        const float* xb = xb0 + (cl << 12);
        float xv[9];
#pragma unroll
        for (int kh = 0; kh < 3; ++kh) {
            int ih = oh + kh - 1;
            bool okr = ((unsigned)ih < 64u);
#pragma unroll
            for (int kw = 0; kw < 3; ++kw) {
                int iw = ow + kw - 1;
                xv[kh * 3 + kw] = (okr && (unsigned)iw < 64u) ? xb[(kh - 1) * 64 + (kw - 1)] : 0.f;
            }
        }
        const float* wp = ofw + (c0 + cl) * 9;       // wave-uniform -> scalar loads
#pragma unroll
        for (int t = 0; t < 9; ++t) {
            float xvt = xv[t];
#pragma unroll
            for (int oc = 0; oc < 27; ++oc)
                acc[oc] = fmaf(xvt, wp[oc * 1152 + t], acc[oc]);
        }
    }
    int sp = (oh << 6) + ow;
#pragma unroll
    for (int oc = 0; oc < 27; ++oc)
        part[((((cg << 2) + n) * 27 + oc) << 12) + sp] = acc[oc];
}

// ---------------- K2: per-(tap,pos) meta, pair-load form ----------------
// wq = slot weights (s0r1, s1r1, s0r2, s1r2); ob = (R1*64+Cb) | (R2*64+Cb)<<16
__global__ __launch_bounds__(256) void posprep(const float* __restrict__ part,
                                               const float* __restrict__ ob,
                                               float4* __restrict__ wq_t,
                                               unsigned* __restrict__ ob_t) {
    int gid = blockIdx.x * 256 + threadIdx.x;        // < 147456
    int k = gid >> 14, pos = gid & 16383;
    int n = pos >> 12, sp = pos & 4095;
    int oh = sp >> 6, ow = sp & 63;

    float oy = ob[2 * k], ox = ob[2 * k + 1], os = ob[18 + k];
#pragma unroll
    for (int cg = 0; cg < 8; ++cg) {
        const float* pb = part + ((((cg << 2) + n) * 27) << 12) + sp;
        oy += pb[(2 * k) << 12];
        ox += pb[(2 * k + 1) << 12];
        os += pb[(18 + k) << 12];
    }
    float m = 1.f / (1.f + expf(-os));
    float py = fminf(fmaxf((float)(oh + k / 3) + oy, 0.f), 65.f);
    float px = fminf(fmaxf((float)(ow + k % 3) + ox, 0.f), 65.f);
    float y1f = floorf(py), x1f = floorf(px);
    float lh = py - y1f, lw = px - x1f;
    float hh = 1.f - lh, hw = 1.f - lw;
    int y1 = (int)y1f, x1 = (int)x1f;
    int r1 = y1 - 1, r2 = y1, c1 = x1 - 1, c2 = x1;  // padded -> real coords; c2 = c1+1
    bool vr1 = (unsigned)r1 < 64u, vr2 = (unsigned)r2 < 64u;
    bool vc1 = (unsigned)c1 < 64u, vc2 = (unsigned)c2 < 64u;
    float w1 = (vr1 && vc1) ? hh * hw * m : 0.f;
    float w2 = (vr1 && vc2) ? hh * lw * m : 0.f;
    float w3 = (vr2 && vc1) ? lh * hw * m : 0.f;
    float w4 = (vr2 && vc2) ? lh * lw * m : 0.f;
    int Cb = min(max(c1, 0), 62);
    bool a0 = (c1 == Cb);                            // corner1 in slot0 (normal case)
    float s0r1 = a0 ? w1 : ((c2 == Cb) ? w2 : 0.f);
    float s1r1 = a0 ? w2 : ((c1 == Cb + 1) ? w1 : 0.f);
    float s0r2 = a0 ? w3 : ((c2 == Cb) ? w4 : 0.f);
    float s1r2 = a0 ? w4 : ((c1 == Cb + 1) ? w3 : 0.f);
    int R1 = min(max(r1, 0), 63), R2 = min(max(r2, 0), 63);
    unsigned o1 = (unsigned)(R1 * 64 + Cb), o2 = (unsigned)(R2 * 64 + Cb);
    wq_t[(k << 14) + pos] = make_float4(s0r1, s1r1, s0r2, s1r2);
    ob_t[(k << 14) + pos] = o1 | (o2 << 16);
}

// ---------------- K3: MFMA gather-GEMM, counted-wait pipeline ----------------
// grid 1024 = 256 pos-tiles(64) x 4 kq; block 256 = 4 waves; wave = 32 pos x 64 o.
// 9 ksteps of 32k; gathers 2-deep in registers; B direct from global (1-step ahead);
// LDS = A hi/lo dbuf 16KB, XOR unit-swizzle; raw s_barrier (no vmcnt drain).
// __launch_bounds__(256,2): VGPR cap 256 — the full pipeline state must NOT spill.
__global__ __launch_bounds__(256, 2) void dcn_main(const float* __restrict__ x,
                                                   const float4* __restrict__ wq_t,
                                                   const unsigned* __restrict__ ob_t,
                                                   const unsigned short* __restrict__ wbh,
                                                   const unsigned short* __restrict__ wbl,
                                                   float* __restrict__ pout) {
    __shared__ short Ah[2][2048];                    // [buf][64 pos][32 k], 16B-unit swizzled
    __shared__ short Al[2][2048];

    int b0 = blockIdx.x;
    int bid = ((b0 & 7) << 7) | (b0 >> 3);           // XCD swizzle (1024 = 8*128)
    int tile = bid >> 2, q = bid & 3;
    int p0 = tile << 6;
    int tid = threadIdx.x;
    int lane = tid & 63, wave = tid >> 6;
    int ph = wave >> 1, ohf = wave & 1;              // pos-half(32), o-half(64)
    int fr = lane & 15, fg = lane >> 4;
    int gp = tid & 63, gc = tid >> 6;                // gather: pos, 8-ch group (gc==wave)
    int pos = p0 + gp;
    int n = pos >> 12;                               // block-uniform (64 | 4096)
    const float* xn = x + ((long)n << 19);
    int S0 = q * 9;

    f32x4 acc[2][4];
#pragma unroll
    for (int i = 0; i < 2; ++i)
#pragma unroll
        for (int j = 0; j < 4; ++j) acc[i][j] = (f32x4)0.f;

    f2 g1[2][8], g2[2][8];
    float4 wv[2];
    bf16x8 bh[4], bl[4];

#define GATHER(P, S_) do {                                                          \
    int t_ = (S_) >> 2;                                                             \
    wv[P] = wq_t[(t_ << 14) + pos];                                                 \
    unsigned obp_ = ob_t[(t_ << 14) + pos];                                         \
    int o1_ = (int)(obp_ & 0xffffu), o2_ = (int)(obp_ >> 16);                       \
    const float* xb_ = xn + ((long)((((S_) & 3) << 5) + (gc << 3)) << 12);          \
    _Pragma("unroll")                                                               \
    for (int e_ = 0; e_ < 8; ++e_) {                                                \
        const float* xc_ = xb_ + (e_ << 12);                                        \
        g1[P][e_] = *(const f2*)(xc_ + o1_);                                        \
        g2[P][e_] = *(const f2*)(xc_ + o2_);                                        \
    }                                                                               \
} while (0)

#define PACK(P, BUF) do {                                                           \
    bf16x8 vh_, vl_;                                                                \
    _Pragma("unroll")                                                               \
    for (int e_ = 0; e_ < 8; ++e_) {                                                \
        float v_ = wv[P].x * g1[P][e_].x + wv[P].y * g1[P][e_].y                    \
                 + wv[P].z * g2[P][e_].x + wv[P].w * g2[P][e_].y;                   \
        unsigned short h_ = f2bf(v_);                                               \
        vh_[e_] = (short)h_;                                                        \
        vl_[e_] = (short)f2bf(v_ - bf2f(h_));                                       \
    }                                                                               \
    int u_ = (gc ^ (gp & 3) ^ ((gp >> 2) & 3) ^ ((gp >> 4) & 3)) & 3;               \
    *(bf16x8*)&Ah[BUF][(gp << 5) + (u_ << 3)] = vh_;                                \
    *(bf16x8*)&Al[BUF][(gp << 5) + (u_ << 3)] = vl_;                                \
} while (0)

#define LOADB(S_) do {                                                              \
    _Pragma("unroll")                                                               \
    for (int j_ = 0; j_ < 4; ++j_) {                                                \
        int ob_ = (ohf << 6) + (j_ << 4) + fr;                                      \
        long a_ = ((long)(S_) << 12) + (ob_ << 5) + (fg << 3);                      \
        bh[j_] = *(const bf16x8*)(wbh + a_);                                        \
        bl[j_] = *(const bf16x8*)(wbl + a_);                                        \
    }                                                                               \
} while (0)

#define STEP(BUF) do {                                                              \
    bf16x8 ah_[2], al_[2];                                                          \
    _Pragma("unroll")                                                               \
    for (int i_ = 0; i_ < 2; ++i_) {                                                \
        int pl_ = (ph << 5) + (i_ << 4) + fr;                                       \
        int u_ = (fg ^ (pl_ & 3) ^ ((pl_ >> 2) & 3) ^ ((pl_ >> 4) & 3)) & 3;        \
        ah_[i_] = *(const bf16x8*)&Ah[BUF][(pl_ << 5) + (u_ << 3)];                 \
        al_[i_] = *(const bf16x8*)&Al[BUF][(pl_ << 5) + (u_ << 3)];                 \
    }                                                                               \
    __builtin_amdgcn_s_setprio(1);                                                  \
    _Pragma("unroll")                                                               \
    for (int j_ = 0; j_ < 4; ++j_) {                                                \
        _Pragma("unroll")                                                           \
        for (int i_ = 0; i_ < 2; ++i_) {                                            \
            acc[i_][j_] = __builtin_amdgcn_mfma_f32_16x16x32_bf16(ah_[i_], bh[j_], acc[i_][j_], 0, 0, 0); \
            acc[i_][j_] = __builtin_amdgcn_mfma_f32_16x16x32_bf16(al_[i_], bh[j_], acc[i_][j_], 0, 0, 0); \
            acc[i_][j_] = __builtin_amdgcn_mfma_f32_16x16x32_bf16(ah_[i_], bl[j_], acc[i_][j_], 0, 0, 0); \
        }                                                                           \
    }                                                                               \
    __builtin_amdgcn_s_setprio(0);                                                  \
} while (0)

// raw barrier: LDS-visibility wait only — NO vmcnt drain (prefetches stay in flight)
#define BAR() do {                                                                  \
    asm volatile("s_waitcnt lgkmcnt(0)" ::: "memory");                              \
    __builtin_amdgcn_sched_barrier(0);                                              \
    __builtin_amdgcn_s_barrier();                                                   \
    __builtin_amdgcn_sched_barrier(0);                                              \
} while (0)

    // prologue: 2-deep gather, 1-deep B, pack step0
    GATHER(0, S0);
    GATHER(1, S0 + 1);
    LOADB(S0);
    PACK(0, 0);
    BAR();

#pragma unroll
    for (int s = 0; s < 9; ++s) {
        if (s + 2 <= 8) GATHER(s & 1, S0 + s + 2);   // refill the set packed last step
        STEP(s & 1);                                 // consumes bh/bl = B(s)
        if (s < 8) {
            LOADB(S0 + s + 1);                       // B one step ahead
            PACK((s + 1) & 1, (s + 1) & 1);          // gathers issued 2 steps ago
            BAR();
        }
    }

    // epilogue: pout[q][o][pos] (o-major) — each lane stores contiguous float4
    float* op = pout + ((long)q << 21);
#pragma unroll
    for (int i = 0; i < 2; ++i) {
        int pp = p0 + (ph << 5) + (i << 4) + (fg << 2);
#pragma unroll
        for (int j = 0; j < 4; ++j) {
            int o = (ohf << 6) + (j << 4) + fr;
            float4 st = make_float4(acc[i][j][0], acc[i][j][1], acc[i][j][2], acc[i][j][3]);
            *(float4*)(op + ((long)o << 14) + pp) = st;
        }
    }
#undef GATHER
#undef PACK
#undef LOADB
#undef STEP
#undef BAR
}

// ---------------- K4: sum 4 K-partials, fully coalesced ----------------
// pout[q][o][pos], pos = n*4096+hw ; out[n][o][hw]. grid 2048 x 256 over float4s.
__global__ __launch_bounds__(256) void combine(const float4* __restrict__ pout4,
                                               float4* __restrict__ out4) {
    int i = blockIdx.x * 256 + threadIdx.x;          // < 524288
    int o = i >> 12, rem = i & 4095;
    int n = rem >> 10, hw4 = rem & 1023;
    float4 a = pout4[i];
    float4 b = pout4[i + (1 << 19)];
    float4 c = pout4[i + (2 << 19)];
    float4 d = pout4[i + (3 << 19)];
    float4 r = make_float4(a.x + b.x + c.x + d.x, a.y + b.y + c.y + d.y,
                           a.z + b.z + c.z + d.z, a.w + b.w + c.w + d.w);
    out4[(n << 17) + (o << 10) + hw4] = r;
}

extern "C" void kernel_launch(void* const* d_in, const int* in_sizes, int n_in,
                              void* d_out, int out_size, void* d_ws, size_t ws_size,
                              hipStream_t stream) {
    const float* x     = (const float*)d_in[0];      // [4,128,64,64]
    const float* ofw   = (const float*)d_in[1];      // [27,128,3,3]
    const float* ob    = (const float*)d_in[2];      // [27]
    const float* dcn_w = (const float*)d_in[3];      // [128,128,3,3]
    float* out = (float*)d_out;                      // [4,128,64,64]

    char* ws = (char*)d_ws;
    // pout (K3/K4) overlaps part (K1/K2) — disjoint lifetimes
    float*          pout = (float*)ws;                        // 33,554,432 B
    float*          part = (float*)ws;                        // 14,155,776 B (overlap)
    float4*         wq_t = (float4*)(ws + 33554432);          //  2,359,296 B
    unsigned*       ob_t = (unsigned*)(ws + 35913728);        //    589,824 B
    unsigned short* wbh  = (unsigned short*)(ws + 36503552);  //    294,912 B
    unsigned short* wbl  = (unsigned short*)(ws + 36798464);  //    294,912 B
    // total 37,093,376 B (< 44.7 MB proven budget)

    offconv_prep<<<dim3(1088), dim3(256), 0, stream>>>(x, ofw, dcn_w, part, wbh, wbl);
    posprep<<<dim3(576), dim3(256), 0, stream>>>(part, ob, wq_t, ob_t);
    dcn_main<<<dim3(1024), dim3(256), 0, stream>>>(x, wq_t, ob_t, wbh, wbl, pout);
    combine<<<dim3(2048), dim3(256), 0, stream>>>((const float4*)pout, (float4*)out);
}